// Round 2
// baseline (167.501 us; speedup 1.0000x reference)
//
#include <hip/hip_runtime.h>
#include <hip/hip_bf16.h>

// b=1, c=256, h=w=64 -> n=4096 pixels, 4 heads, hd=64, 32 groups x 8 ch.
// scale = hd^-0.5 = 0.125, folded into Wq (K0) and bq (K1 epilogue).
#define NPIX 4096
#define CCH  256
#define HD   64
#define GSIZE 32768   // 8 ch * 4096 pix per group

typedef __bf16 bf16x8 __attribute__((ext_vector_type(8)));
typedef __bf16 bf16x4 __attribute__((ext_vector_type(4)));
typedef __bf16 bf16x2 __attribute__((ext_vector_type(2)));
typedef float  f32x4  __attribute__((ext_vector_type(4)));
typedef unsigned int uint32x4 __attribute__((ext_vector_type(4)));

#define XPITCH 264   // X/F panel pitch (bf16) for K1/K3

// MFMA 16x16x32_bf16 layouts (verified m89/m91):
//   A[m=lane&15][k=quad*8+j]; B[k=quad*8+j][n=lane&15]; C: row=quad*4+reg, col=lane&15

__device__ __forceinline__ unsigned pack_bf16x2(float lo, float hi)
{
    bf16x2 v;
    v[0] = (__bf16)lo;
    v[1] = (__bf16)hi;
    return __builtin_bit_cast(unsigned, v);
}

// ---------------------------------------------------------------------------
// K0: blocks 0..255: per-(group,1/8th) partial sums -> psum/pssq[256].
//     blocks 256..319: weight fp32->bf16 convert (Wq scaled 0.125).
// ---------------------------------------------------------------------------
__global__ __launch_bounds__(256) void stats_wconv(
    const float* __restrict__ X,
    const float* __restrict__ Wq, const float* __restrict__ Wk,
    const float* __restrict__ Wv, const float* __restrict__ Wp,
    float* __restrict__ psum, float* __restrict__ pssq, __bf16* __restrict__ Wb)
{
    const int bid = blockIdx.x, t = threadIdx.x;
    if (bid < 256) {
        const float* base = X + bid * 4096;   // (g = bid>>3, seg = bid&7)
        float sum = 0.f, ssq = 0.f;
        #pragma unroll
        for (int k = 0; k < 4; ++k) {
            float4 v = *(const float4*)(base + t * 4 + k * 1024);
            sum += v.x + v.y + v.z + v.w;
            ssq += v.x * v.x + v.y * v.y + v.z * v.z + v.w * v.w;
        }
        #pragma unroll
        for (int off = 1; off < 64; off <<= 1) {
            sum += __shfl_xor(sum, off);
            ssq += __shfl_xor(ssq, off);
        }
        __shared__ float red[2][4];
        const int wv = t >> 6;
        if ((t & 63) == 0) { red[0][wv] = sum; red[1][wv] = ssq; }
        __syncthreads();
        if (t == 0) {
            psum[bid] = red[0][0] + red[0][1] + red[0][2] + red[0][3];
            pssq[bid] = red[1][0] + red[1][1] + red[1][2] + red[1][3];
        }
    } else {
        const int j0 = (bid - 256) * 4096 + t * 16;
        const int m  = j0 >> 16;
        const float* W = (m == 0) ? Wq : (m == 1) ? Wk : (m == 2) ? Wv : Wp;
        const float sc = (m == 0) ? 0.125f : 1.f;
        const int off = j0 & 65535;
        #pragma unroll
        for (int k = 0; k < 4; ++k) {
            float4 v = *(const float4*)(W + off + k * 4);
            bf16x4 o;
            o[0] = (__bf16)(v.x * sc); o[1] = (__bf16)(v.y * sc);
            o[2] = (__bf16)(v.z * sc); o[3] = (__bf16)(v.w * sc);
            *(bf16x4*)(Wb + m * 65536 + off + k * 4) = o;
        }
    }
}

// ---------------------------------------------------------------------------
// K1: fused GroupNorm-apply + QKV MFMA GEMM. grid (64 pixblk, 6: z*2+och).
// (unchanged from R8)
// ---------------------------------------------------------------------------
__global__ __launch_bounds__(256) void gn_qkv(
    const float* __restrict__ X, const float* __restrict__ gamma,
    const float* __restrict__ beta,
    const float* __restrict__ psum, const float* __restrict__ pssq,
    const __bf16* __restrict__ Wb,
    const float* __restrict__ bq, const float* __restrict__ bk,
    const float* __restrict__ bv,
    __bf16* __restrict__ Qb, __bf16* __restrict__ Kb, __bf16* __restrict__ Vb)
{
    __shared__ __bf16 tile[64 * XPITCH];
    __shared__ float al[256], bl[256];

    const int t = threadIdx.x, lane = t & 63, wave = t >> 6;
    const int l16 = lane & 15, quad = lane >> 4;
    const int p0 = blockIdx.x * 64;
    const int z = blockIdx.y >> 1, och = blockIdx.y & 1;

    {
        const int g = t >> 3;
        float s = 0.f, q = 0.f;
        #pragma unroll
        for (int j = 0; j < 8; ++j) { s += psum[g * 8 + j]; q += pssq[g * 8 + j]; }
        const float mu  = s * (1.f / GSIZE);
        const float var = q * (1.f / GSIZE) - mu * mu;
        const float a = gamma[t] * rsqrtf(var + 1e-6f);
        al[t] = a;
        bl[t] = beta[t] - mu * a;
    }
    __syncthreads();

    #pragma unroll 4
    for (int i = 0; i < 16; ++i) {
        const int c4 = wave * 64 + i * 4;
        f32x4 a4 = *(const f32x4*)(al + c4);
        f32x4 b4 = *(const f32x4*)(bl + c4);
        bf16x4 pk;
        pk[0] = (__bf16)(X[(c4 + 0) * NPIX + p0 + lane] * a4[0] + b4[0]);
        pk[1] = (__bf16)(X[(c4 + 1) * NPIX + p0 + lane] * a4[1] + b4[1]);
        pk[2] = (__bf16)(X[(c4 + 2) * NPIX + p0 + lane] * a4[2] + b4[2]);
        pk[3] = (__bf16)(X[(c4 + 3) * NPIX + p0 + lane] * a4[3] + b4[3]);
        *(bf16x4*)(tile + lane * XPITCH + c4) = pk;
    }
    __syncthreads();

    const int pw = wave * 16;
    bf16x8 xf[8];
    #pragma unroll
    for (int kc = 0; kc < 8; ++kc)
        xf[kc] = *(const bf16x8*)(tile + (pw + l16) * XPITCH + kc * 32 + quad * 8);

    const __bf16* Wz = Wb + z * 65536;
    const float* bias = (z == 0) ? bq : (z == 1) ? bk : bv;

    if (z < 2) {
        const float qs = (z == 0) ? 0.125f : 1.f;
        __bf16* dst = (z == 0) ? Qb : Kb;
        #pragma unroll
        for (int grp = 0; grp < 2; ++grp) {
            f32x4 acc[4] = {};
            #pragma unroll
            for (int kc = 0; kc < 8; ++kc) {
                #pragma unroll
                for (int u = 0; u < 4; ++u) {
                    bf16x8 wf = *(const bf16x8*)(Wz + (och * 128 + (grp * 4 + u) * 16 + l16) * CCH + kc * 32 + quad * 8);
                    acc[u] = __builtin_amdgcn_mfma_f32_16x16x32_bf16(wf, xf[kc], acc[u], 0, 0, 0);
                }
            }
            #pragma unroll
            for (int u = 0; u < 4; ++u) {
                const int ot = och * 8 + grp * 4 + u;
                f32x4 bz = *(const f32x4*)(bias + och * 128 + (grp * 4 + u) * 16 + quad * 4);
                bf16x4 o;
                o[0] = (__bf16)(acc[u][0] + bz[0] * qs);
                o[1] = (__bf16)(acc[u][1] + bz[1] * qs);
                o[2] = (__bf16)(acc[u][2] + bz[2] * qs);
                o[3] = (__bf16)(acc[u][3] + bz[3] * qs);
                const int head = ot >> 2, dloc = (ot & 3) * 16 + quad * 4;
                *(bf16x4*)(dst + head * (NPIX * HD) + (p0 + pw + l16) * HD + dloc) = o;
            }
        }
    } else {
        #pragma unroll
        for (int grp = 0; grp < 2; ++grp) {
            f32x4 acc[4] = {};
            #pragma unroll
            for (int kc = 0; kc < 8; ++kc) {
                #pragma unroll
                for (int u = 0; u < 4; ++u) {
                    bf16x8 wf = *(const bf16x8*)(Wz + (och * 128 + (grp * 4 + u) * 16 + l16) * CCH + kc * 32 + quad * 8);
                    acc[u] = __builtin_amdgcn_mfma_f32_16x16x32_bf16(xf[kc], wf, acc[u], 0, 0, 0);
                }
            }
            #pragma unroll
            for (int u = 0; u < 4; ++u) {
                const int oc = och * 128 + (grp * 4 + u) * 16 + l16;
                const float bz = bias[oc];
                bf16x4 o;
                o[0] = (__bf16)(acc[u][0] + bz); o[1] = (__bf16)(acc[u][1] + bz);
                o[2] = (__bf16)(acc[u][2] + bz); o[3] = (__bf16)(acc[u][3] + bz);
                *(bf16x4*)(Vb + oc * NPIX + p0 + pw + quad * 4) = o;
            }
        }
    }
}

// ---------------------------------------------------------------------------
// K2 (R10): LDS-free attention, now at 2 blocks/CU for latency hiding.
// R9 post-mortem: zero-LDS loop landed at ~39 us (predicted ~17). Cause: 256
// blocks = 1 wave/SIMD; the QK->exp->PV phases are dependent within a wave, so
// matrix pipe idles during exp and every latency is exposed. R10: split each
// q-tile in half -> 512 blocks x 32 q-rows, per-wave state halves (VGPR ~170,
// capped 256 via launch_bounds(256,2)), merge LDS 35 KB -> 2 blocks/CU =
// 2 waves/SIMD at independent phases. K/V L2 traffic doubles (64 MB/XCD,
// ~3.2 TB/s < 4.3 TB/s ceiling). setprio(1) wraps MFMA clusters (T5: pays
// when waves have role diversity, which 2 co-resident blocks now provide).
// ---------------------------------------------------------------------------
__global__ __launch_bounds__(256, 2) void attn_mfma(
    const __bf16* __restrict__ Qb, const __bf16* __restrict__ Kb,
    const __bf16* __restrict__ Vb, __bf16* __restrict__ Sb)
{
    __shared__ __align__(16) float co[4 * 32 * 68];  // 34816 B merge buffer
    __shared__ float cl[4 * 32];

    const int t = threadIdx.x, lane = t & 63, wave = t >> 6;
    const int l16 = lane & 15, quad = lane >> 4;

    const int bid  = blockIdx.x;
    const int head = (bid & 7) >> 1;                   // XCD-pair pinning
    const int qidx = ((bid >> 3) << 1) | (bid & 1);    // 0..127
    const int p0   = qidx * 32;

    const __bf16* Qh = Qb + head * (NPIX * HD);
    const __bf16* Kh = Kb + head * (NPIX * HD) + (wave * 32 + l16) * HD + quad * 8;
    const __bf16* Vh = Vb + head * (HD * NPIX) + l16 * NPIX + wave * 32 + quad * 8;

    // Q B-frags for 32 shared rows: B[k=d][n=row16]
    bf16x8 qf[2][2];
    #pragma unroll
    for (int rt = 0; rt < 2; ++rt) {
        const __bf16* qp = Qh + (p0 + rt * 16 + l16) * HD + quad * 8;
        qf[rt][0] = *(const bf16x8*)(qp);
        qf[rt][1] = *(const bf16x8*)(qp + 32);
    }

    bf16x8 ones;
    #pragma unroll
    for (int j = 0; j < 8; ++j) ones[j] = (__bf16)1.0f;

    f32x4 l_acc[2] = {};
    f32x4 o_acc[4][2] = {};   // [dt][rt]

    auto ldKV = [&](int it, bf16x8 (&kf)[2][2], bf16x8 (&vf)[4]) {
        const __bf16* kp = Kh + it * (128 * HD);
        kf[0][0] = *(const bf16x8*)(kp);
        kf[0][1] = *(const bf16x8*)(kp + 32);
        kf[1][0] = *(const bf16x8*)(kp + 16 * HD);
        kf[1][1] = *(const bf16x8*)(kp + 16 * HD + 32);
        const __bf16* vp = Vh + it * 128;
        #pragma unroll
        for (int dt = 0; dt < 4; ++dt)
            vf[dt] = *(const bf16x8*)(vp + dt * (16 * NPIX));
    };

    auto step = [&](const bf16x8 (&kf)[2][2], const bf16x8 (&vf)[4]) {
        // S^T = K Q^T : C(key_local = kt*16+quad*4+r, row = rt*16+l16)
        f32x4 st0[2] = {}, st1[2] = {};
        __builtin_amdgcn_s_setprio(1);
        #pragma unroll
        for (int rt = 0; rt < 2; ++rt) {
            st0[rt] = __builtin_amdgcn_mfma_f32_16x16x32_bf16(kf[0][0], qf[rt][0], st0[rt], 0, 0, 0);
            st0[rt] = __builtin_amdgcn_mfma_f32_16x16x32_bf16(kf[0][1], qf[rt][1], st0[rt], 0, 0, 0);
            st1[rt] = __builtin_amdgcn_mfma_f32_16x16x32_bf16(kf[1][0], qf[rt][0], st1[rt], 0, 0, 0);
            st1[rt] = __builtin_amdgcn_mfma_f32_16x16x32_bf16(kf[1][1], qf[rt][1], st1[rt], 0, 0, 0);
        }
        __builtin_amdgcn_s_setprio(0);
        #pragma unroll
        for (int rt = 0; rt < 2; ++rt) {
            // lane (l16,q): a0/a1 = kt0 keys {4q..4q+3}, b0/b1 = kt1 keys {16+4q..}
            unsigned a0 = pack_bf16x2(__expf(st0[rt][0]), __expf(st0[rt][1]));
            unsigned a1 = pack_bf16x2(__expf(st0[rt][2]), __expf(st0[rt][3]));
            unsigned b0 = pack_bf16x2(__expf(st1[rt][0]), __expf(st1[rt][1]));
            unsigned b1 = pack_bf16x2(__expf(st1[rt][2]), __expf(st1[rt][3]));
            // swap32 then swap16: (a0,b0) -> (w0,w2); (a1,b1) -> (w1,w3)
            asm("v_permlane32_swap_b32 %0, %1" : "+v"(a0), "+v"(b0));
            asm("v_permlane32_swap_b32 %0, %1" : "+v"(a1), "+v"(b1));
            asm("v_permlane16_swap_b32 %0, %1" : "+v"(a0), "+v"(b0));
            asm("v_permlane16_swap_b32 %0, %1" : "+v"(a1), "+v"(b1));
            uint32x4 w;
            w[0] = a0; w[1] = a1; w[2] = b0; w[3] = b1;
            const bf16x8 bp = __builtin_bit_cast(bf16x8, w);  // B[k=key32][n=row]
            __builtin_amdgcn_s_setprio(1);
            l_acc[rt] = __builtin_amdgcn_mfma_f32_16x16x32_bf16(ones, bp, l_acc[rt], 0, 0, 0);
            #pragma unroll
            for (int dt = 0; dt < 4; ++dt)
                o_acc[dt][rt] = __builtin_amdgcn_mfma_f32_16x16x32_bf16(vf[dt], bp, o_acc[dt][rt], 0, 0, 0);
            __builtin_amdgcn_s_setprio(0);
        }
    };

    bf16x8 ka[2][2], va[4], kb[2][2], vb[4];
    ldKV(0, ka, va);
    #pragma unroll 1
    for (int it = 0; it < 32; it += 2) {
        ldKV(it + 1, kb, vb);
        step(ka, va);
        if (it + 2 < 32) ldKV(it + 2, ka, va);
        step(kb, vb);
    }

    // ---- in-LDS 4-way key merge ----
    #pragma unroll
    for (int dt = 0; dt < 4; ++dt)
        #pragma unroll
        for (int rt = 0; rt < 2; ++rt)
            *(f32x4*)(co + wave * 2176 + (rt * 16 + l16) * 68 + dt * 16 + quad * 4) = o_acc[dt][rt];
    if (quad == 0) {
        #pragma unroll
        for (int rt = 0; rt < 2; ++rt)
            cl[wave * 32 + rt * 16 + l16] = l_acc[rt][0];
    }
    __syncthreads();

    {
        const int row = t >> 3, dc = (t & 7) * 8;
        const float l = cl[row] + cl[32 + row] + cl[64 + row] + cl[96 + row];
        const float inv = 1.f / l;
        f32x4 s0 = {0.f, 0.f, 0.f, 0.f}, s1 = {0.f, 0.f, 0.f, 0.f};
        #pragma unroll
        for (int w = 0; w < 4; ++w) {
            s0 += *(const f32x4*)(co + w * 2176 + row * 68 + dc);
            s1 += *(const f32x4*)(co + w * 2176 + row * 68 + dc + 4);
        }
        bf16x8 o;
        #pragma unroll
        for (int j = 0; j < 4; ++j) {
            o[j]     = (__bf16)(s0[j] * inv);
            o[j + 4] = (__bf16)(s1[j] * inv);
        }
        *(bf16x8*)(Sb + (p0 + row) * CCH + head * HD + dc) = o;
    }
}

// ---------------------------------------------------------------------------
// K3: proj bf16 MFMA GEMM + bias + residual, fp32 out [c][pix].
// (unchanged from R8)
// ---------------------------------------------------------------------------
__global__ __launch_bounds__(256) void gemm_proj(
    const __bf16* __restrict__ Sb, const __bf16* __restrict__ Wpb,
    const float* __restrict__ bias, const float* __restrict__ X,
    float* __restrict__ Out)
{
    __shared__ __bf16 Bs[32 * XPITCH];

    const int t = threadIdx.x, lane = t & 63, wave = t >> 6;
    const int l16 = lane & 15, quad = lane >> 4;
    const int p0  = blockIdx.x * 32;
    const int och = blockIdx.y;

    #pragma unroll
    for (int pg = 0; pg < 4; ++pg) {
        bf16x8 v = *(const bf16x8*)(Sb + t * NPIX + p0 + pg * 8);
        #pragma unroll
        for (int j = 0; j < 8; ++j)
            Bs[(pg * 8 + j) * XPITCH + t] = v[j];
    }
    __syncthreads();

    const int pixset = wave & 1, ocset = wave >> 1;
    bf16x8 af[8];
    #pragma unroll
    for (int kc = 0; kc < 8; ++kc)
        af[kc] = *(const bf16x8*)(Bs + (pixset * 16 + l16) * XPITCH + kc * 32 + quad * 8);

    #pragma unroll
    for (int u = 0; u < 4; ++u) {
        f32x4 acc = {};
        const int oc_t = och * 128 + ocset * 64 + u * 16;
        #pragma unroll
        for (int kc = 0; kc < 8; ++kc) {
            bf16x8 wf = *(const bf16x8*)(Wpb + (oc_t + l16) * CCH + kc * 32 + quad * 8);
            acc = __builtin_amdgcn_mfma_f32_16x16x32_bf16(af[kc], wf, acc, 0, 0, 0);
        }
        const int oc  = oc_t + l16;
        const int pix = p0 + pixset * 16 + quad * 4;
        const float bz = bias[oc];
        f32x4 r4 = *(const f32x4*)(X + oc * NPIX + pix);
        f32x4 y;
        y[0] = acc[0] + bz + r4[0];
        y[1] = acc[1] + bz + r4[1];
        y[2] = acc[2] + bz + r4[2];
        y[3] = acc[3] + bz + r4[3];
        *(f32x4*)(Out + oc * NPIX + pix) = y;
    }
}

// ---------------------------------------------------------------------------
extern "C" void kernel_launch(void* const* d_in, const int* in_sizes, int n_in,
                              void* d_out, int out_size, void* d_ws, size_t ws_size,
                              hipStream_t stream)
{
    const float* x     = (const float*)d_in[0];
    const float* gamma = (const float*)d_in[1];
    const float* beta  = (const float*)d_in[2];
    const float* Wq    = (const float*)d_in[3];
    const float* bq    = (const float*)d_in[4];
    const float* Wk    = (const float*)d_in[5];
    const float* bk    = (const float*)d_in[6];
    const float* Wv    = (const float*)d_in[7];
    const float* bv    = (const float*)d_in[8];
    const float* Wp    = (const float*)d_in[9];
    const float* bp    = (const float*)d_in[10];
    float* out = (float*)d_out;

    char* ws = (char*)d_ws;
    float*  psum = (float*)(ws);                // 1KB stats partial sums
    float*  pssq = (float*)(ws + 1024);         // 1KB
    __bf16* Wb   = (__bf16*)(ws + 65536);       // 512KB bf16 4x[256][256]
    __bf16* Qb   = (__bf16*)(ws + (1 << 20));   // 2MB bf16 [head][pix][64]
    __bf16* Kb   = (__bf16*)(ws + (3 << 20));   // 2MB bf16 [head][pix][64]
    __bf16* Vb   = (__bf16*)(ws + (5 << 20));   // 2MB bf16 [c][pix]
    __bf16* Sb   = (__bf16*)(ws + (7 << 20));   // 2MB bf16 flat F

    stats_wconv<<<320, 256, 0, stream>>>(x, Wq, Wk, Wv, Wp, psum, pssq, Wb);

    dim3 gq(64, 6);
    gn_qkv<<<gq, 256, 0, stream>>>(x, gamma, beta, psum, pssq, Wb,
                                   bq, bk, bv, Qb, Kb, Vb);

    attn_mfma<<<512, 256, 0, stream>>>(Qb, Kb, Vb, Sb);

    dim3 gp(128, 2);
    gemm_proj<<<gp, 256, 0, stream>>>(Sb, Wb + 3 * 65536, bp, x, out);
}

// Round 3
// 147.045 us; speedup vs baseline: 1.1391x; 1.1391x over previous
//
#include <hip/hip_runtime.h>
#include <hip/hip_bf16.h>

// b=1, c=256, h=w=64 -> n=4096 pixels, 4 heads, hd=64, 32 groups x 8 ch.
// scale = hd^-0.5 = 0.125, folded into Wq (K0) and bq (K1 epilogue).
#define NPIX 4096
#define CCH  256
#define HD   64
#define GSIZE 32768   // 8 ch * 4096 pix per group

typedef __bf16 bf16x8 __attribute__((ext_vector_type(8)));
typedef __bf16 bf16x4 __attribute__((ext_vector_type(4)));
typedef __bf16 bf16x2 __attribute__((ext_vector_type(2)));
typedef float  f32x4  __attribute__((ext_vector_type(4)));
typedef unsigned int uint32x4 __attribute__((ext_vector_type(4)));

#define XPITCH 264   // X/F panel pitch (bf16) for K1/K3

// MFMA 16x16x32_bf16 layouts (verified m89/m91):
//   A[m=lane&15][k=quad*8+j]; B[k=quad*8+j][n=lane&15]; C: row=quad*4+reg, col=lane&15

__device__ __forceinline__ unsigned pack_bf16x2(float lo, float hi)
{
    bf16x2 v;
    v[0] = (__bf16)lo;
    v[1] = (__bf16)hi;
    return __builtin_bit_cast(unsigned, v);
}

// ---------------------------------------------------------------------------
// K0: blocks 0..255: per-(group,1/8th) partial sums -> psum/pssq[256].
//     blocks 256..319: weight fp32->bf16 convert (Wq scaled 0.125).
// ---------------------------------------------------------------------------
__global__ __launch_bounds__(256) void stats_wconv(
    const float* __restrict__ X,
    const float* __restrict__ Wq, const float* __restrict__ Wk,
    const float* __restrict__ Wv, const float* __restrict__ Wp,
    float* __restrict__ psum, float* __restrict__ pssq, __bf16* __restrict__ Wb)
{
    const int bid = blockIdx.x, t = threadIdx.x;
    if (bid < 256) {
        const float* base = X + bid * 4096;   // (g = bid>>3, seg = bid&7)
        float sum = 0.f, ssq = 0.f;
        #pragma unroll
        for (int k = 0; k < 4; ++k) {
            float4 v = *(const float4*)(base + t * 4 + k * 1024);
            sum += v.x + v.y + v.z + v.w;
            ssq += v.x * v.x + v.y * v.y + v.z * v.z + v.w * v.w;
        }
        #pragma unroll
        for (int off = 1; off < 64; off <<= 1) {
            sum += __shfl_xor(sum, off);
            ssq += __shfl_xor(ssq, off);
        }
        __shared__ float red[2][4];
        const int wv = t >> 6;
        if ((t & 63) == 0) { red[0][wv] = sum; red[1][wv] = ssq; }
        __syncthreads();
        if (t == 0) {
            psum[bid] = red[0][0] + red[0][1] + red[0][2] + red[0][3];
            pssq[bid] = red[1][0] + red[1][1] + red[1][2] + red[1][3];
        }
    } else {
        const int j0 = (bid - 256) * 4096 + t * 16;
        const int m  = j0 >> 16;
        const float* W = (m == 0) ? Wq : (m == 1) ? Wk : (m == 2) ? Wv : Wp;
        const float sc = (m == 0) ? 0.125f : 1.f;
        const int off = j0 & 65535;
        #pragma unroll
        for (int k = 0; k < 4; ++k) {
            float4 v = *(const float4*)(W + off + k * 4);
            bf16x4 o;
            o[0] = (__bf16)(v.x * sc); o[1] = (__bf16)(v.y * sc);
            o[2] = (__bf16)(v.z * sc); o[3] = (__bf16)(v.w * sc);
            *(bf16x4*)(Wb + m * 65536 + off + k * 4) = o;
        }
    }
}

// ---------------------------------------------------------------------------
// K1: fused GroupNorm-apply + QKV MFMA GEMM. grid (64 pixblk, 6: z*2+och).
// (unchanged from R8)
// ---------------------------------------------------------------------------
__global__ __launch_bounds__(256) void gn_qkv(
    const float* __restrict__ X, const float* __restrict__ gamma,
    const float* __restrict__ beta,
    const float* __restrict__ psum, const float* __restrict__ pssq,
    const __bf16* __restrict__ Wb,
    const float* __restrict__ bq, const float* __restrict__ bk,
    const float* __restrict__ bv,
    __bf16* __restrict__ Qb, __bf16* __restrict__ Kb, __bf16* __restrict__ Vb)
{
    __shared__ __bf16 tile[64 * XPITCH];
    __shared__ float al[256], bl[256];

    const int t = threadIdx.x, lane = t & 63, wave = t >> 6;
    const int l16 = lane & 15, quad = lane >> 4;
    const int p0 = blockIdx.x * 64;
    const int z = blockIdx.y >> 1, och = blockIdx.y & 1;

    {
        const int g = t >> 3;
        float s = 0.f, q = 0.f;
        #pragma unroll
        for (int j = 0; j < 8; ++j) { s += psum[g * 8 + j]; q += pssq[g * 8 + j]; }
        const float mu  = s * (1.f / GSIZE);
        const float var = q * (1.f / GSIZE) - mu * mu;
        const float a = gamma[t] * rsqrtf(var + 1e-6f);
        al[t] = a;
        bl[t] = beta[t] - mu * a;
    }
    __syncthreads();

    #pragma unroll 4
    for (int i = 0; i < 16; ++i) {
        const int c4 = wave * 64 + i * 4;
        f32x4 a4 = *(const f32x4*)(al + c4);
        f32x4 b4 = *(const f32x4*)(bl + c4);
        bf16x4 pk;
        pk[0] = (__bf16)(X[(c4 + 0) * NPIX + p0 + lane] * a4[0] + b4[0]);
        pk[1] = (__bf16)(X[(c4 + 1) * NPIX + p0 + lane] * a4[1] + b4[1]);
        pk[2] = (__bf16)(X[(c4 + 2) * NPIX + p0 + lane] * a4[2] + b4[2]);
        pk[3] = (__bf16)(X[(c4 + 3) * NPIX + p0 + lane] * a4[3] + b4[3]);
        *(bf16x4*)(tile + lane * XPITCH + c4) = pk;
    }
    __syncthreads();

    const int pw = wave * 16;
    bf16x8 xf[8];
    #pragma unroll
    for (int kc = 0; kc < 8; ++kc)
        xf[kc] = *(const bf16x8*)(tile + (pw + l16) * XPITCH + kc * 32 + quad * 8);

    const __bf16* Wz = Wb + z * 65536;
    const float* bias = (z == 0) ? bq : (z == 1) ? bk : bv;

    if (z < 2) {
        const float qs = (z == 0) ? 0.125f : 1.f;
        __bf16* dst = (z == 0) ? Qb : Kb;
        #pragma unroll
        for (int grp = 0; grp < 2; ++grp) {
            f32x4 acc[4] = {};
            #pragma unroll
            for (int kc = 0; kc < 8; ++kc) {
                #pragma unroll
                for (int u = 0; u < 4; ++u) {
                    bf16x8 wf = *(const bf16x8*)(Wz + (och * 128 + (grp * 4 + u) * 16 + l16) * CCH + kc * 32 + quad * 8);
                    acc[u] = __builtin_amdgcn_mfma_f32_16x16x32_bf16(wf, xf[kc], acc[u], 0, 0, 0);
                }
            }
            #pragma unroll
            for (int u = 0; u < 4; ++u) {
                const int ot = och * 8 + grp * 4 + u;
                f32x4 bz = *(const f32x4*)(bias + och * 128 + (grp * 4 + u) * 16 + quad * 4);
                bf16x4 o;
                o[0] = (__bf16)(acc[u][0] + bz[0] * qs);
                o[1] = (__bf16)(acc[u][1] + bz[1] * qs);
                o[2] = (__bf16)(acc[u][2] + bz[2] * qs);
                o[3] = (__bf16)(acc[u][3] + bz[3] * qs);
                const int head = ot >> 2, dloc = (ot & 3) * 16 + quad * 4;
                *(bf16x4*)(dst + head * (NPIX * HD) + (p0 + pw + l16) * HD + dloc) = o;
            }
        }
    } else {
        #pragma unroll
        for (int grp = 0; grp < 2; ++grp) {
            f32x4 acc[4] = {};
            #pragma unroll
            for (int kc = 0; kc < 8; ++kc) {
                #pragma unroll
                for (int u = 0; u < 4; ++u) {
                    bf16x8 wf = *(const bf16x8*)(Wz + (och * 128 + (grp * 4 + u) * 16 + l16) * CCH + kc * 32 + quad * 8);
                    acc[u] = __builtin_amdgcn_mfma_f32_16x16x32_bf16(xf[kc], wf, acc[u], 0, 0, 0);
                }
            }
            #pragma unroll
            for (int u = 0; u < 4; ++u) {
                const int oc = och * 128 + (grp * 4 + u) * 16 + l16;
                const float bz = bias[oc];
                bf16x4 o;
                o[0] = (__bf16)(acc[u][0] + bz); o[1] = (__bf16)(acc[u][1] + bz);
                o[2] = (__bf16)(acc[u][2] + bz); o[3] = (__bf16)(acc[u][3] + bz);
                *(bf16x4*)(Vb + oc * NPIX + p0 + pw + quad * 4) = o;
            }
        }
    }
}

// ---------------------------------------------------------------------------
// K2 (R11): key-split LDS-free attention -> fp32 partials + merge kernel.
// R10 post-mortem: q-split doubled L2 load traffic (512 MB) AND the (256,2)
// bound let the allocator sink the prefetch loads (VGPR 80) -> pipeline dead,
// 64 us. R11 keeps R9's per-wave shape (64 q-rows, VGPR ~140, register
// double-buffer) but splits KEYS across 2 blocks: 512 blocks x 16 key-tiles,
// total traffic back to 256 MB, 2 blocks/CU (LDS 70.7 KB). Co-resident blocks
// (bid, bid+256) share head+keyhalf -> same L2 working set. sched_barrier(0)
// pins prefetch issue before the previous tile's compute (anti-sinking).
// Blocks write un-normalized fp32 (o,l) partials; attn_merge sums halves and
// normalizes into Sb with the exact same address math -> K3 interface
// unchanged.
// ---------------------------------------------------------------------------
__global__ __launch_bounds__(256, 2) void attn_partial(
    const __bf16* __restrict__ Qb, const __bf16* __restrict__ Kb,
    const __bf16* __restrict__ Vb, float* __restrict__ Op,
    float* __restrict__ Lp)
{
    __shared__ __align__(16) float co[4 * 64 * 68];  // 69632 B merge buffer
    __shared__ float cl[4 * 64];

    const int t = threadIdx.x, lane = t & 63, wave = t >> 6;
    const int l16 = lane & 15, quad = lane >> 4;

    const int bid  = blockIdx.x;
    const int head = (bid & 7) >> 1;                    // XCD pinning (bits 1-2)
    const int half = (bid >> 3) & 1;                    // key half (bit 3)
    const int qt   = ((bid >> 4) << 1) | (bid & 1);     // 0..63 (bits 0,4..8)
    const int p0   = qt * 64;
    const int kt0  = half * 16;                         // first of 16 key-tiles

    const __bf16* Qh = Qb + head * (NPIX * HD);
    const __bf16* Kh = Kb + head * (NPIX * HD) + (wave * 32 + l16) * HD + quad * 8;
    const __bf16* Vh = Vb + head * (HD * NPIX) + l16 * NPIX + wave * 32 + quad * 8;

    // Q B-frags for 64 shared rows: B[k=d][n=row16]
    bf16x8 qf[4][2];
    #pragma unroll
    for (int rt = 0; rt < 4; ++rt) {
        const __bf16* qp = Qh + (p0 + rt * 16 + l16) * HD + quad * 8;
        qf[rt][0] = *(const bf16x8*)(qp);
        qf[rt][1] = *(const bf16x8*)(qp + 32);
    }

    bf16x8 ones;
    #pragma unroll
    for (int j = 0; j < 8; ++j) ones[j] = (__bf16)1.0f;

    f32x4 l_acc[4] = {};
    f32x4 o_acc[4][4] = {};   // [dt][rt]

    auto ldKV = [&](int it, bf16x8 (&kf)[2][2], bf16x8 (&vf)[4]) {
        const __bf16* kp = Kh + it * (128 * HD);
        kf[0][0] = *(const bf16x8*)(kp);
        kf[0][1] = *(const bf16x8*)(kp + 32);
        kf[1][0] = *(const bf16x8*)(kp + 16 * HD);
        kf[1][1] = *(const bf16x8*)(kp + 16 * HD + 32);
        const __bf16* vp = Vh + it * 128;
        #pragma unroll
        for (int dt = 0; dt < 4; ++dt)
            vf[dt] = *(const bf16x8*)(vp + dt * (16 * NPIX));
    };

    auto step = [&](const bf16x8 (&kf)[2][2], const bf16x8 (&vf)[4]) {
        // S^T = K Q^T : C(key_local = kt*16+quad*4+r, row = rt*16+l16)
        f32x4 st0[4] = {}, st1[4] = {};
        __builtin_amdgcn_s_setprio(1);
        #pragma unroll
        for (int rt = 0; rt < 4; ++rt) {
            st0[rt] = __builtin_amdgcn_mfma_f32_16x16x32_bf16(kf[0][0], qf[rt][0], st0[rt], 0, 0, 0);
            st0[rt] = __builtin_amdgcn_mfma_f32_16x16x32_bf16(kf[0][1], qf[rt][1], st0[rt], 0, 0, 0);
            st1[rt] = __builtin_amdgcn_mfma_f32_16x16x32_bf16(kf[1][0], qf[rt][0], st1[rt], 0, 0, 0);
            st1[rt] = __builtin_amdgcn_mfma_f32_16x16x32_bf16(kf[1][1], qf[rt][1], st1[rt], 0, 0, 0);
        }
        __builtin_amdgcn_s_setprio(0);
        #pragma unroll
        for (int rt = 0; rt < 4; ++rt) {
            // lane (l16,q): a0/a1 = kt0 keys {4q..4q+3}, b0/b1 = kt1 keys {16+4q..}
            unsigned a0 = pack_bf16x2(__expf(st0[rt][0]), __expf(st0[rt][1]));
            unsigned a1 = pack_bf16x2(__expf(st0[rt][2]), __expf(st0[rt][3]));
            unsigned b0 = pack_bf16x2(__expf(st1[rt][0]), __expf(st1[rt][1]));
            unsigned b1 = pack_bf16x2(__expf(st1[rt][2]), __expf(st1[rt][3]));
            // swap32 then swap16: (a0,b0) -> (w0,w2); (a1,b1) -> (w1,w3)
            asm("v_permlane32_swap_b32 %0, %1" : "+v"(a0), "+v"(b0));
            asm("v_permlane32_swap_b32 %0, %1" : "+v"(a1), "+v"(b1));
            asm("v_permlane16_swap_b32 %0, %1" : "+v"(a0), "+v"(b0));
            asm("v_permlane16_swap_b32 %0, %1" : "+v"(a1), "+v"(b1));
            uint32x4 w;
            w[0] = a0; w[1] = a1; w[2] = b0; w[3] = b1;
            const bf16x8 bp = __builtin_bit_cast(bf16x8, w);  // B[k=key32][n=row]
            __builtin_amdgcn_s_setprio(1);
            l_acc[rt] = __builtin_amdgcn_mfma_f32_16x16x32_bf16(ones, bp, l_acc[rt], 0, 0, 0);
            #pragma unroll
            for (int dt = 0; dt < 4; ++dt)
                o_acc[dt][rt] = __builtin_amdgcn_mfma_f32_16x16x32_bf16(vf[dt], bp, o_acc[dt][rt], 0, 0, 0);
            __builtin_amdgcn_s_setprio(0);
        }
    };

    bf16x8 ka[2][2], va[4], kb[2][2], vb[4];
    ldKV(kt0, ka, va);
    #pragma unroll 1
    for (int it = kt0; it < kt0 + 16; it += 2) {
        ldKV(it + 1, kb, vb);
        __builtin_amdgcn_sched_barrier(0);   // pin prefetch issue before compute
        step(ka, va);
        if (it + 2 < kt0 + 16) ldKV(it + 2, ka, va);
        __builtin_amdgcn_sched_barrier(0);
        step(kb, vb);
    }

    // ---- in-LDS 4-way wave merge, then fp32 partial store ----
    #pragma unroll
    for (int dt = 0; dt < 4; ++dt)
        #pragma unroll
        for (int rt = 0; rt < 4; ++rt)
            *(f32x4*)(co + wave * 4352 + (rt * 16 + l16) * 68 + dt * 16 + quad * 4) = o_acc[dt][rt];
    if (quad == 0) {
        #pragma unroll
        for (int rt = 0; rt < 4; ++rt)
            cl[wave * 64 + rt * 16 + l16] = l_acc[rt][0];
    }
    __syncthreads();

    {
        const int row = t >> 2, dc = (t & 3) * 16;
        f32x4 s[4];
        #pragma unroll
        for (int j = 0; j < 4; ++j) {
            s[j] = f32x4{0.f, 0.f, 0.f, 0.f};
            #pragma unroll
            for (int w = 0; w < 4; ++w)
                s[j] += *(const f32x4*)(co + w * 4352 + row * 68 + dc + j * 4);
        }
        float* dsto = Op + half * (NPIX * CCH) + (p0 + row) * CCH + head * HD + dc;
        #pragma unroll
        for (int j = 0; j < 4; ++j)
            *(f32x4*)(dsto + j * 4) = s[j];
        if ((t & 3) == 0) {
            const float l = cl[row] + cl[64 + row] + cl[128 + row] + cl[192 + row];
            Lp[half * 16384 + head * 4096 + p0 + row] = l;
        }
    }
}

// ---------------------------------------------------------------------------
// K2b: merge the two key-half partials and normalize -> Sb (bf16).
// Address-decodes (P, head) from the linear index with the same convention
// attn_partial used to write, so it is layout-agnostic by construction.
// ---------------------------------------------------------------------------
__global__ __launch_bounds__(256) void attn_merge(
    const float* __restrict__ Op, const float* __restrict__ Lp,
    __bf16* __restrict__ Sb)
{
    const int idx = (blockIdx.x * 256 + threadIdx.x) * 8;
    const int P = idx >> 8;                 // q-row as written by attn_partial
    const int head = (idx >> 6) & 3;
    const float l = Lp[head * 4096 + P] + Lp[16384 + head * 4096 + P];
    const float inv = 1.f / l;
    f32x4 a0 = *(const f32x4*)(Op + idx);
    f32x4 a1 = *(const f32x4*)(Op + idx + 4);
    f32x4 b0 = *(const f32x4*)(Op + NPIX * CCH + idx);
    f32x4 b1 = *(const f32x4*)(Op + NPIX * CCH + idx + 4);
    bf16x8 o;
    #pragma unroll
    for (int j = 0; j < 4; ++j) {
        o[j]     = (__bf16)((a0[j] + b0[j]) * inv);
        o[j + 4] = (__bf16)((a1[j] + b1[j]) * inv);
    }
    *(bf16x8*)(Sb + idx) = o;
}

// ---------------------------------------------------------------------------
// K3: proj bf16 MFMA GEMM + bias + residual, fp32 out [c][pix].
// (unchanged from R8)
// ---------------------------------------------------------------------------
__global__ __launch_bounds__(256) void gemm_proj(
    const __bf16* __restrict__ Sb, const __bf16* __restrict__ Wpb,
    const float* __restrict__ bias, const float* __restrict__ X,
    float* __restrict__ Out)
{
    __shared__ __bf16 Bs[32 * XPITCH];

    const int t = threadIdx.x, lane = t & 63, wave = t >> 6;
    const int l16 = lane & 15, quad = lane >> 4;
    const int p0  = blockIdx.x * 32;
    const int och = blockIdx.y;

    #pragma unroll
    for (int pg = 0; pg < 4; ++pg) {
        bf16x8 v = *(const bf16x8*)(Sb + t * NPIX + p0 + pg * 8);
        #pragma unroll
        for (int j = 0; j < 8; ++j)
            Bs[(pg * 8 + j) * XPITCH + t] = v[j];
    }
    __syncthreads();

    const int pixset = wave & 1, ocset = wave >> 1;
    bf16x8 af[8];
    #pragma unroll
    for (int kc = 0; kc < 8; ++kc)
        af[kc] = *(const bf16x8*)(Bs + (pixset * 16 + l16) * XPITCH + kc * 32 + quad * 8);

    #pragma unroll
    for (int u = 0; u < 4; ++u) {
        f32x4 acc = {};
        const int oc_t = och * 128 + ocset * 64 + u * 16;
        #pragma unroll
        for (int kc = 0; kc < 8; ++kc) {
            bf16x8 wf = *(const bf16x8*)(Wpb + (oc_t + l16) * CCH + kc * 32 + quad * 8);
            acc = __builtin_amdgcn_mfma_f32_16x16x32_bf16(af[kc], wf, acc, 0, 0, 0);
        }
        const int oc  = oc_t + l16;
        const int pix = p0 + pixset * 16 + quad * 4;
        const float bz = bias[oc];
        f32x4 r4 = *(const f32x4*)(X + oc * NPIX + pix);
        f32x4 y;
        y[0] = acc[0] + bz + r4[0];
        y[1] = acc[1] + bz + r4[1];
        y[2] = acc[2] + bz + r4[2];
        y[3] = acc[3] + bz + r4[3];
        *(f32x4*)(Out + oc * NPIX + pix) = y;
    }
}

// ---------------------------------------------------------------------------
extern "C" void kernel_launch(void* const* d_in, const int* in_sizes, int n_in,
                              void* d_out, int out_size, void* d_ws, size_t ws_size,
                              hipStream_t stream)
{
    const float* x     = (const float*)d_in[0];
    const float* gamma = (const float*)d_in[1];
    const float* beta  = (const float*)d_in[2];
    const float* Wq    = (const float*)d_in[3];
    const float* bq    = (const float*)d_in[4];
    const float* Wk    = (const float*)d_in[5];
    const float* bk    = (const float*)d_in[6];
    const float* Wv    = (const float*)d_in[7];
    const float* bv    = (const float*)d_in[8];
    const float* Wp    = (const float*)d_in[9];
    const float* bp    = (const float*)d_in[10];
    float* out = (float*)d_out;

    char* ws = (char*)d_ws;
    float*  psum = (float*)(ws);                // 1KB stats partial sums
    float*  pssq = (float*)(ws + 1024);         // 1KB
    __bf16* Wb   = (__bf16*)(ws + 65536);       // 512KB bf16 4x[256][256]
    __bf16* Qb   = (__bf16*)(ws + (1 << 20));   // 2MB bf16 [head][pix][64]
    __bf16* Kb   = (__bf16*)(ws + (3 << 20));   // 2MB bf16 [head][pix][64]
    __bf16* Vb   = (__bf16*)(ws + (5 << 20));   // 2MB bf16 [c][pix]
    __bf16* Sb   = (__bf16*)(ws + (7 << 20));   // 2MB bf16 flat F
    float*  Op   = (float*)(ws + (16 << 20));   // 8MB f32 2x key-half partials
    float*  Lp   = (float*)(ws + (25 << 20));   // 128KB f32 2x[head][pix] sums

    stats_wconv<<<320, 256, 0, stream>>>(x, Wq, Wk, Wv, Wp, psum, pssq, Wb);

    dim3 gq(64, 6);
    gn_qkv<<<gq, 256, 0, stream>>>(x, gamma, beta, psum, pssq, Wb,
                                   bq, bk, bv, Qb, Kb, Vb);

    attn_partial<<<512, 256, 0, stream>>>(Qb, Kb, Vb, Op, Lp);
    attn_merge<<<512, 256, 0, stream>>>(Op, Lp, Sb);

    dim3 gp(128, 2);
    gemm_proj<<<gp, 256, 0, stream>>>(Sb, Wb + 3 * 65536, bp, x, out);
}

// Round 4
// 140.881 us; speedup vs baseline: 1.1890x; 1.0438x over previous
//
#include <hip/hip_runtime.h>
#include <hip/hip_bf16.h>

// b=1, c=256, h=w=64 -> n=4096 pixels, 4 heads, hd=64, 32 groups x 8 ch.
// scale = hd^-0.5 * log2(e) = 0.18033688, folded into Wq (K0) and bq (K1
// epilogue) so attention softmax uses native v_exp_f32 (exp2) directly.
#define NPIX 4096
#define CCH  256
#define HD   64
#define GSIZE 32768   // 8 ch * 4096 pix per group

#define QSCALE 0.18033688f   // 0.125 * log2(e); softmax in base-2 domain

typedef __bf16 bf16x8 __attribute__((ext_vector_type(8)));
typedef __bf16 bf16x4 __attribute__((ext_vector_type(4)));
typedef __bf16 bf16x2 __attribute__((ext_vector_type(2)));
typedef float  f32x4  __attribute__((ext_vector_type(4)));
typedef unsigned int uint32x4 __attribute__((ext_vector_type(4)));

#define XPITCH 264   // X/F panel pitch (bf16) for K1/K3

#if __has_builtin(__builtin_amdgcn_exp2f)
#define EXP2(x) __builtin_amdgcn_exp2f(x)
#else
#define EXP2(x) __expf((x) * 0.6931471805599453f)
#endif

// MFMA 16x16x32_bf16 layouts (verified m89/m91):
//   A[m=lane&15][k=quad*8+j]; B[k=quad*8+j][n=lane&15]; C: row=quad*4+reg, col=lane&15

__device__ __forceinline__ unsigned pack_bf16x2(float lo, float hi)
{
    bf16x2 v;
    v[0] = (__bf16)lo;
    v[1] = (__bf16)hi;
    return __builtin_bit_cast(unsigned, v);
}

// ---------------------------------------------------------------------------
// K0: blocks 0..255: per-(group,1/8th) partial sums -> psum/pssq[256].
//     blocks 256..319: weight fp32->bf16 convert (Wq scaled by QSCALE).
// ---------------------------------------------------------------------------
__global__ __launch_bounds__(256) void stats_wconv(
    const float* __restrict__ X,
    const float* __restrict__ Wq, const float* __restrict__ Wk,
    const float* __restrict__ Wv, const float* __restrict__ Wp,
    float* __restrict__ psum, float* __restrict__ pssq, __bf16* __restrict__ Wb)
{
    const int bid = blockIdx.x, t = threadIdx.x;
    if (bid < 256) {
        const float* base = X + bid * 4096;   // (g = bid>>3, seg = bid&7)
        float sum = 0.f, ssq = 0.f;
        #pragma unroll
        for (int k = 0; k < 4; ++k) {
            float4 v = *(const float4*)(base + t * 4 + k * 1024);
            sum += v.x + v.y + v.z + v.w;
            ssq += v.x * v.x + v.y * v.y + v.z * v.z + v.w * v.w;
        }
        #pragma unroll
        for (int off = 1; off < 64; off <<= 1) {
            sum += __shfl_xor(sum, off);
            ssq += __shfl_xor(ssq, off);
        }
        __shared__ float red[2][4];
        const int wv = t >> 6;
        if ((t & 63) == 0) { red[0][wv] = sum; red[1][wv] = ssq; }
        __syncthreads();
        if (t == 0) {
            psum[bid] = red[0][0] + red[0][1] + red[0][2] + red[0][3];
            pssq[bid] = red[1][0] + red[1][1] + red[1][2] + red[1][3];
        }
    } else {
        const int j0 = (bid - 256) * 4096 + t * 16;
        const int m  = j0 >> 16;
        const float* W = (m == 0) ? Wq : (m == 1) ? Wk : (m == 2) ? Wv : Wp;
        const float sc = (m == 0) ? QSCALE : 1.f;
        const int off = j0 & 65535;
        #pragma unroll
        for (int k = 0; k < 4; ++k) {
            float4 v = *(const float4*)(W + off + k * 4);
            bf16x4 o;
            o[0] = (__bf16)(v.x * sc); o[1] = (__bf16)(v.y * sc);
            o[2] = (__bf16)(v.z * sc); o[3] = (__bf16)(v.w * sc);
            *(bf16x4*)(Wb + m * 65536 + off + k * 4) = o;
        }
    }
}

// ---------------------------------------------------------------------------
// K1: fused GroupNorm-apply + QKV MFMA GEMM. grid (64 pixblk, 6: z*2+och).
// (unchanged except qs = QSCALE)
// ---------------------------------------------------------------------------
__global__ __launch_bounds__(256) void gn_qkv(
    const float* __restrict__ X, const float* __restrict__ gamma,
    const float* __restrict__ beta,
    const float* __restrict__ psum, const float* __restrict__ pssq,
    const __bf16* __restrict__ Wb,
    const float* __restrict__ bq, const float* __restrict__ bk,
    const float* __restrict__ bv,
    __bf16* __restrict__ Qb, __bf16* __restrict__ Kb, __bf16* __restrict__ Vb)
{
    __shared__ __bf16 tile[64 * XPITCH];
    __shared__ float al[256], bl[256];

    const int t = threadIdx.x, lane = t & 63, wave = t >> 6;
    const int l16 = lane & 15, quad = lane >> 4;
    const int p0 = blockIdx.x * 64;
    const int z = blockIdx.y >> 1, och = blockIdx.y & 1;

    {
        const int g = t >> 3;
        float s = 0.f, q = 0.f;
        #pragma unroll
        for (int j = 0; j < 8; ++j) { s += psum[g * 8 + j]; q += pssq[g * 8 + j]; }
        const float mu  = s * (1.f / GSIZE);
        const float var = q * (1.f / GSIZE) - mu * mu;
        const float a = gamma[t] * rsqrtf(var + 1e-6f);
        al[t] = a;
        bl[t] = beta[t] - mu * a;
    }
    __syncthreads();

    #pragma unroll 4
    for (int i = 0; i < 16; ++i) {
        const int c4 = wave * 64 + i * 4;
        f32x4 a4 = *(const f32x4*)(al + c4);
        f32x4 b4 = *(const f32x4*)(bl + c4);
        bf16x4 pk;
        pk[0] = (__bf16)(X[(c4 + 0) * NPIX + p0 + lane] * a4[0] + b4[0]);
        pk[1] = (__bf16)(X[(c4 + 1) * NPIX + p0 + lane] * a4[1] + b4[1]);
        pk[2] = (__bf16)(X[(c4 + 2) * NPIX + p0 + lane] * a4[2] + b4[2]);
        pk[3] = (__bf16)(X[(c4 + 3) * NPIX + p0 + lane] * a4[3] + b4[3]);
        *(bf16x4*)(tile + lane * XPITCH + c4) = pk;
    }
    __syncthreads();

    const int pw = wave * 16;
    bf16x8 xf[8];
    #pragma unroll
    for (int kc = 0; kc < 8; ++kc)
        xf[kc] = *(const bf16x8*)(tile + (pw + l16) * XPITCH + kc * 32 + quad * 8);

    const __bf16* Wz = Wb + z * 65536;
    const float* bias = (z == 0) ? bq : (z == 1) ? bk : bv;

    if (z < 2) {
        const float qs = (z == 0) ? QSCALE : 1.f;
        __bf16* dst = (z == 0) ? Qb : Kb;
        #pragma unroll
        for (int grp = 0; grp < 2; ++grp) {
            f32x4 acc[4] = {};
            #pragma unroll
            for (int kc = 0; kc < 8; ++kc) {
                #pragma unroll
                for (int u = 0; u < 4; ++u) {
                    bf16x8 wf = *(const bf16x8*)(Wz + (och * 128 + (grp * 4 + u) * 16 + l16) * CCH + kc * 32 + quad * 8);
                    acc[u] = __builtin_amdgcn_mfma_f32_16x16x32_bf16(wf, xf[kc], acc[u], 0, 0, 0);
                }
            }
            #pragma unroll
            for (int u = 0; u < 4; ++u) {
                const int ot = och * 8 + grp * 4 + u;
                f32x4 bz = *(const f32x4*)(bias + och * 128 + (grp * 4 + u) * 16 + quad * 4);
                bf16x4 o;
                o[0] = (__bf16)(acc[u][0] + bz[0] * qs);
                o[1] = (__bf16)(acc[u][1] + bz[1] * qs);
                o[2] = (__bf16)(acc[u][2] + bz[2] * qs);
                o[3] = (__bf16)(acc[u][3] + bz[3] * qs);
                const int head = ot >> 2, dloc = (ot & 3) * 16 + quad * 4;
                *(bf16x4*)(dst + head * (NPIX * HD) + (p0 + pw + l16) * HD + dloc) = o;
            }
        }
    } else {
        #pragma unroll
        for (int grp = 0; grp < 2; ++grp) {
            f32x4 acc[4] = {};
            #pragma unroll
            for (int kc = 0; kc < 8; ++kc) {
                #pragma unroll
                for (int u = 0; u < 4; ++u) {
                    bf16x8 wf = *(const bf16x8*)(Wz + (och * 128 + (grp * 4 + u) * 16 + l16) * CCH + kc * 32 + quad * 8);
                    acc[u] = __builtin_amdgcn_mfma_f32_16x16x32_bf16(xf[kc], wf, acc[u], 0, 0, 0);
                }
            }
            #pragma unroll
            for (int u = 0; u < 4; ++u) {
                const int oc = och * 128 + (grp * 4 + u) * 16 + l16;
                const float bz = bias[oc];
                bf16x4 o;
                o[0] = (__bf16)(acc[u][0] + bz); o[1] = (__bf16)(acc[u][1] + bz);
                o[2] = (__bf16)(acc[u][2] + bz); o[3] = (__bf16)(acc[u][3] + bz);
                *(bf16x4*)(Vb + oc * NPIX + p0 + pw + quad * 4) = o;
            }
        }
    }
}

// ---------------------------------------------------------------------------
// K2 (R12): zero-LDS attention, R9 grid (256 blocks, no merge kernel), with:
//  - 2-deep register prefetch: three NAMED K/V buffer sets rotated by a
//    3x-unrolled loop (16 loads in flight spanning 2 compute phases;
//    launch_bounds(256,1) = 512-reg budget so no pressure motive to sink).
//  - base-2 softmax: S already scaled by log2(e) upstream -> P = exp2(S),
//    removing 32 v_mul_f32/tile from the exp critical chain (native v_exp).
//  - no setprio churn / sched_barriers: 1 block/CU has nothing to arbitrate
//    (m190 null) and pins only hurt cross-step ILP (QK(t+1) MFMA can now
//    overlap exp(t) trans ops).
// R9/R11 post-mortem: per-tile-instance cost ~3000 cyc invariant across
// 1 vs 2 waves/SIMD -> correlated/in-chain stalls, not coverable by waves;
// this round targets the chain itself.
// ---------------------------------------------------------------------------
__global__ __launch_bounds__(256, 1) void attn_mfma(
    const __bf16* __restrict__ Qb, const __bf16* __restrict__ Kb,
    const __bf16* __restrict__ Vb, __bf16* __restrict__ Sb)
{
    __shared__ __align__(16) float co[4 * 64 * 68];  // 69632 B merge buffer
    __shared__ float cl[4 * 64];

    const int t = threadIdx.x, lane = t & 63, wave = t >> 6;
    const int l16 = lane & 15, quad = lane >> 4;

    const int bid  = blockIdx.x;
    const int head = (bid & 7) >> 1;                   // XCD-pair pinning
    const int qt   = ((bid >> 3) << 1) | (bid & 1);    // 0..63
    const int p0   = qt * 64;

    const __bf16* Qh = Qb + head * (NPIX * HD);
    const __bf16* Kh = Kb + head * (NPIX * HD) + (wave * 32 + l16) * HD + quad * 8;
    const __bf16* Vh = Vb + head * (HD * NPIX) + l16 * NPIX + wave * 32 + quad * 8;

    // Q B-frags for 64 shared rows: B[k=d][n=row16]
    bf16x8 qf[4][2];
    #pragma unroll
    for (int rt = 0; rt < 4; ++rt) {
        const __bf16* qp = Qh + (p0 + rt * 16 + l16) * HD + quad * 8;
        qf[rt][0] = *(const bf16x8*)(qp);
        qf[rt][1] = *(const bf16x8*)(qp + 32);
    }

    bf16x8 ones;
    #pragma unroll
    for (int j = 0; j < 8; ++j) ones[j] = (__bf16)1.0f;

    f32x4 l_acc[4] = {};
    f32x4 o_acc[4][4] = {};   // [dt][rt]

    // load tile 'it' into one named buffer set (8 x global_load_dwordx4)
    auto ldKV = [&](int it,
                    bf16x8& k0, bf16x8& k1, bf16x8& k2, bf16x8& k3,
                    bf16x8& v0, bf16x8& v1, bf16x8& v2, bf16x8& v3) {
        const __bf16* kp = Kh + it * (128 * HD);
        k0 = *(const bf16x8*)(kp);
        k1 = *(const bf16x8*)(kp + 32);
        k2 = *(const bf16x8*)(kp + 16 * HD);
        k3 = *(const bf16x8*)(kp + 16 * HD + 32);
        const __bf16* vp = Vh + it * 128;
        v0 = *(const bf16x8*)(vp);
        v1 = *(const bf16x8*)(vp + 16 * NPIX);
        v2 = *(const bf16x8*)(vp + 32 * NPIX);
        v3 = *(const bf16x8*)(vp + 48 * NPIX);
    };

    auto step = [&](bf16x8 k0, bf16x8 k1, bf16x8 k2, bf16x8 k3,
                    bf16x8 v0, bf16x8 v1, bf16x8 v2, bf16x8 v3) {
        // S^T = K Q^T : C(key_local = kt*16+quad*4+r, row = rt*16+l16)
        f32x4 st0[4] = {}, st1[4] = {};
        #pragma unroll
        for (int rt = 0; rt < 4; ++rt) {
            st0[rt] = __builtin_amdgcn_mfma_f32_16x16x32_bf16(k0, qf[rt][0], st0[rt], 0, 0, 0);
            st0[rt] = __builtin_amdgcn_mfma_f32_16x16x32_bf16(k1, qf[rt][1], st0[rt], 0, 0, 0);
            st1[rt] = __builtin_amdgcn_mfma_f32_16x16x32_bf16(k2, qf[rt][0], st1[rt], 0, 0, 0);
            st1[rt] = __builtin_amdgcn_mfma_f32_16x16x32_bf16(k3, qf[rt][1], st1[rt], 0, 0, 0);
        }
        #pragma unroll
        for (int rt = 0; rt < 4; ++rt) {
            // P = 2^(S') ; lane (l16,q): a0/a1 = kt0 keys, b0/b1 = kt1 keys
            unsigned a0 = pack_bf16x2(EXP2(st0[rt][0]), EXP2(st0[rt][1]));
            unsigned a1 = pack_bf16x2(EXP2(st0[rt][2]), EXP2(st0[rt][3]));
            unsigned b0 = pack_bf16x2(EXP2(st1[rt][0]), EXP2(st1[rt][1]));
            unsigned b1 = pack_bf16x2(EXP2(st1[rt][2]), EXP2(st1[rt][3]));
            // swap32 then swap16: (a0,b0) -> (w0,w2); (a1,b1) -> (w1,w3)
            asm("v_permlane32_swap_b32 %0, %1" : "+v"(a0), "+v"(b0));
            asm("v_permlane32_swap_b32 %0, %1" : "+v"(a1), "+v"(b1));
            asm("v_permlane16_swap_b32 %0, %1" : "+v"(a0), "+v"(b0));
            asm("v_permlane16_swap_b32 %0, %1" : "+v"(a1), "+v"(b1));
            uint32x4 w;
            w[0] = a0; w[1] = a1; w[2] = b0; w[3] = b1;
            const bf16x8 bp = __builtin_bit_cast(bf16x8, w);  // B[k=key32][n=row]
            l_acc[rt] = __builtin_amdgcn_mfma_f32_16x16x32_bf16(ones, bp, l_acc[rt], 0, 0, 0);
            o_acc[0][rt] = __builtin_amdgcn_mfma_f32_16x16x32_bf16(v0, bp, o_acc[0][rt], 0, 0, 0);
            o_acc[1][rt] = __builtin_amdgcn_mfma_f32_16x16x32_bf16(v1, bp, o_acc[1][rt], 0, 0, 0);
            o_acc[2][rt] = __builtin_amdgcn_mfma_f32_16x16x32_bf16(v2, bp, o_acc[2][rt], 0, 0, 0);
            o_acc[3][rt] = __builtin_amdgcn_mfma_f32_16x16x32_bf16(v3, bp, o_acc[3][rt], 0, 0, 0);
        }
    };

    // three named buffer sets, 2-deep prefetch, 3x-unrolled rotation
    bf16x8 ka0, ka1, ka2, ka3, va0, va1, va2, va3;
    bf16x8 kb0, kb1, kb2, kb3, vb0, vb1, vb2, vb3;
    bf16x8 kc0, kc1, kc2, kc3, vc0, vc1, vc2, vc3;

    ldKV(0, ka0, ka1, ka2, ka3, va0, va1, va2, va3);
    ldKV(1, kb0, kb1, kb2, kb3, vb0, vb1, vb2, vb3);

    #pragma unroll 1
    for (int it = 0; it < 30; it += 3) {
        ldKV(it + 2, kc0, kc1, kc2, kc3, vc0, vc1, vc2, vc3);
        step(ka0, ka1, ka2, ka3, va0, va1, va2, va3);
        ldKV(it + 3, ka0, ka1, ka2, ka3, va0, va1, va2, va3);
        step(kb0, kb1, kb2, kb3, vb0, vb1, vb2, vb3);
        ldKV(it + 4, kb0, kb1, kb2, kb3, vb0, vb1, vb2, vb3);
        step(kc0, kc1, kc2, kc3, vc0, vc1, vc2, vc3);
    }
    // tiles 30 (in A, loaded at it=27) and 31 (in B)
    step(ka0, ka1, ka2, ka3, va0, va1, va2, va3);
    step(kb0, kb1, kb2, kb3, vb0, vb1, vb2, vb3);

    // ---- in-LDS 4-way key merge ----
    #pragma unroll
    for (int dt = 0; dt < 4; ++dt)
        #pragma unroll
        for (int rt = 0; rt < 4; ++rt)
            *(f32x4*)(co + wave * 4352 + (rt * 16 + l16) * 68 + dt * 16 + quad * 4) = o_acc[dt][rt];
    if (quad == 0) {
        #pragma unroll
        for (int rt = 0; rt < 4; ++rt)
            cl[wave * 64 + rt * 16 + l16] = l_acc[rt][0];
    }
    __syncthreads();

    {
        const int row = t >> 2, dc = (t & 3) * 16;
        const float l = cl[row] + cl[64 + row] + cl[128 + row] + cl[192 + row];
        const float inv = 1.f / l;
        f32x4 s[4];
        #pragma unroll
        for (int j = 0; j < 4; ++j) {
            s[j] = f32x4{0.f, 0.f, 0.f, 0.f};
            #pragma unroll
            for (int w = 0; w < 4; ++w)
                s[j] += *(const f32x4*)(co + w * 4352 + row * 68 + dc + j * 4);
        }
        bf16x8 o1, o2;
        #pragma unroll
        for (int j = 0; j < 4; ++j) {
            o1[j]     = (__bf16)(s[0][j] * inv);
            o1[j + 4] = (__bf16)(s[1][j] * inv);
            o2[j]     = (__bf16)(s[2][j] * inv);
            o2[j + 4] = (__bf16)(s[3][j] * inv);
        }
        __bf16* dst = Sb + (p0 + row) * CCH + head * HD + dc;
        *(bf16x8*)(dst)     = o1;
        *(bf16x8*)(dst + 8) = o2;
    }
}

// ---------------------------------------------------------------------------
// K3: proj bf16 MFMA GEMM + bias + residual, fp32 out [c][pix].
// (unchanged from R8)
// ---------------------------------------------------------------------------
__global__ __launch_bounds__(256) void gemm_proj(
    const __bf16* __restrict__ Sb, const __bf16* __restrict__ Wpb,
    const float* __restrict__ bias, const float* __restrict__ X,
    float* __restrict__ Out)
{
    __shared__ __bf16 Bs[32 * XPITCH];

    const int t = threadIdx.x, lane = t & 63, wave = t >> 6;
    const int l16 = lane & 15, quad = lane >> 4;
    const int p0  = blockIdx.x * 32;
    const int och = blockIdx.y;

    #pragma unroll
    for (int pg = 0; pg < 4; ++pg) {
        bf16x8 v = *(const bf16x8*)(Sb + t * NPIX + p0 + pg * 8);
        #pragma unroll
        for (int j = 0; j < 8; ++j)
            Bs[(pg * 8 + j) * XPITCH + t] = v[j];
    }
    __syncthreads();

    const int pixset = wave & 1, ocset = wave >> 1;
    bf16x8 af[8];
    #pragma unroll
    for (int kc = 0; kc < 8; ++kc)
        af[kc] = *(const bf16x8*)(Bs + (pixset * 16 + l16) * XPITCH + kc * 32 + quad * 8);

    #pragma unroll
    for (int u = 0; u < 4; ++u) {
        f32x4 acc = {};
        const int oc_t = och * 128 + ocset * 64 + u * 16;
        #pragma unroll
        for (int kc = 0; kc < 8; ++kc) {
            bf16x8 wf = *(const bf16x8*)(Wpb + (oc_t + l16) * CCH + kc * 32 + quad * 8);
            acc = __builtin_amdgcn_mfma_f32_16x16x32_bf16(af[kc], wf, acc, 0, 0, 0);
        }
        const int oc  = oc_t + l16;
        const int pix = p0 + pixset * 16 + quad * 4;
        const float bz = bias[oc];
        f32x4 r4 = *(const f32x4*)(X + oc * NPIX + pix);
        f32x4 y;
        y[0] = acc[0] + bz + r4[0];
        y[1] = acc[1] + bz + r4[1];
        y[2] = acc[2] + bz + r4[2];
        y[3] = acc[3] + bz + r4[3];
        *(f32x4*)(Out + oc * NPIX + pix) = y;
    }
}

// ---------------------------------------------------------------------------
extern "C" void kernel_launch(void* const* d_in, const int* in_sizes, int n_in,
                              void* d_out, int out_size, void* d_ws, size_t ws_size,
                              hipStream_t stream)
{
    const float* x     = (const float*)d_in[0];
    const float* gamma = (const float*)d_in[1];
    const float* beta  = (const float*)d_in[2];
    const float* Wq    = (const float*)d_in[3];
    const float* bq    = (const float*)d_in[4];
    const float* Wk    = (const float*)d_in[5];
    const float* bk    = (const float*)d_in[6];
    const float* Wv    = (const float*)d_in[7];
    const float* bv    = (const float*)d_in[8];
    const float* Wp    = (const float*)d_in[9];
    const float* bp    = (const float*)d_in[10];
    float* out = (float*)d_out;

    char* ws = (char*)d_ws;
    float*  psum = (float*)(ws);                // 1KB stats partial sums
    float*  pssq = (float*)(ws + 1024);         // 1KB
    __bf16* Wb   = (__bf16*)(ws + 65536);       // 512KB bf16 4x[256][256]
    __bf16* Qb   = (__bf16*)(ws + (1 << 20));   // 2MB bf16 [head][pix][64]
    __bf16* Kb   = (__bf16*)(ws + (3 << 20));   // 2MB bf16 [head][pix][64]
    __bf16* Vb   = (__bf16*)(ws + (5 << 20));   // 2MB bf16 [c][pix]
    __bf16* Sb   = (__bf16*)(ws + (7 << 20));   // 2MB bf16 flat F

    stats_wconv<<<320, 256, 0, stream>>>(x, Wq, Wk, Wv, Wp, psum, pssq, Wb);

    dim3 gq(64, 6);
    gn_qkv<<<gq, 256, 0, stream>>>(x, gamma, beta, psum, pssq, Wb,
                                   bq, bk, bv, Qb, Kb, Vb);

    attn_mfma<<<256, 256, 0, stream>>>(Qb, Kb, Vb, Sb);

    dim3 gp(128, 2);
    gemm_proj<<<gp, 256, 0, stream>>>(Sb, Wb + 3 * 65536, bp, x, out);
}